// Round 13
// baseline (1162.765 us; speedup 1.0000x reference)
//
#include <hip/hip_runtime.h>
#include <cmath>

#define B_  32
#define T_  250
#define E_  256
#define U_  1024
#define FU_ 4096   // 4*U
#define VK_ 1280   // virtual K = U + E  ( [rk0 ; k0] )
#define NT_ 40     // W k-tiles (32 h-tiles + 8 x-tiles)
#define NB_ 128    // step-kernel blocks (each: 8 units x 4 gates = 32 z-cols)

typedef __attribute__((ext_vector_type(8)))  __bf16 bf16x8;
typedef __attribute__((ext_vector_type(4)))  float  f32x4;

__device__ __forceinline__ float sigf(float x)  { return 1.f / (1.f + __expf(-x)); }
__device__ __forceinline__ float tanhfast(float x) { return 1.f - 2.f / (1.f + __expf(2.f * x)); }

// ---------------------------------------------------------------------------
// One-time: transpose weights into MFMA B-fragment order, bf16 hi (proven
// r12). NEW indexing for 128 blocks x 2 col-frags:
// wfrag[(((bi*40 + K)*2 + cf)*64 + l)*8 + j], bi=u>>3, cf=(g*8+(u&7))>>4.
// ---------------------------------------------------------------------------
__global__ __launch_bounds__(256) void wsplit_kernel(
    const float* __restrict__ rk0, const float* __restrict__ k0,
    __bf16* __restrict__ wfh)
{
    __shared__ float tile[32][65];
    const int tid = threadIdx.x;
    const int jt  = blockIdx.x & 63;
    const int kt  = blockIdx.x >> 6;
    const int gk0 = kt * 32;
    const int j0  = jt * 64;

    {
        const int c = tid & 63, r4 = tid >> 6;
        #pragma unroll
        for (int i = 0; i < 8; ++i) {
            const int r  = r4 * 8 + i;
            const int gk = gk0 + r;
            const float* src = (gk < U_) ? (rk0 + (size_t)gk * FU_ + j0 + c)
                                         : (k0 + (size_t)(gk - U_) * FU_ + j0 + c);
            tile[r][c] = *src;
        }
    }
    __syncthreads();
    {
        const int j_loc = tid >> 2, kseg = tid & 3;
        bf16x8 hi;
        #pragma unroll
        for (int i = 0; i < 8; ++i)
            hi[i] = (__bf16)tile[kseg * 8 + i][j_loc];
        const int col = j0 + j_loc;
        const int g   = col >> 10;
        const int u   = col & 1023;
        const int bi  = u >> 3;             // 0..127
        const int cl  = g * 8 + (u & 7);    // 0..31 within block
        const int cf  = cl >> 4;            // col-fragment
        const int cc  = cl & 15;
        const int l   = kseg * 16 + cc;
        const size_t off = ((((size_t)bi * NT_ + kt) * 2 + cf) * 64 + l) * 8;
        *(bf16x8*)(wfh + off) = hi;
    }
}

// ---------------------------------------------------------------------------
// One-time: x-fragments (bf16 hi) for ALL 250 steps (proven r11-12).
// xf[(((t*8 + Kx)*2 + mt)*64 + lane)*8 + j].
// ---------------------------------------------------------------------------
__global__ __launch_bounds__(256) void xsplit_all(
    const int* __restrict__ tokens, const float* __restrict__ emb,
    __bf16* __restrict__ xf)
{
    const int t   = blockIdx.x;
    const int tid = threadIdx.x;
    const int b   = tid >> 3;
    const int kc  = (tid & 7) * 32;
    const int tok = tokens[b * T_ + t];
    const float* ep = emb + (size_t)tok * E_ + kc;
    const int Kx = kc >> 5;
    const int mt = b >> 4;
    #pragma unroll
    for (int g8 = 0; g8 < 4; ++g8) {
        bf16x8 hi;
        #pragma unroll
        for (int j = 0; j < 8; ++j) hi[j] = (__bf16)ep[g8 * 8 + j];
        const int lane2 = g8 * 16 + (b & 15);
        const size_t off = ((((size_t)t * 8 + Kx) * 2 + mt) * 64 + lane2) * 8;
        *(bf16x8*)(xf + off) = hi;
    }
}

// ---------------------------------------------------------------------------
// Fused LSTM step, launched 250x (stream order = grid barrier; proven
// cheapest sync: cg 42us r5, LLC barrier 15us r10, relaunch ~2us).
// Grid 128 x 512. Block bi = units [8bi,8bi+8) x 4 gates = 32 z-cols
// (2 col-frags) over full K=1280. Wave = kq (8 x 5 k-tiles). Per tile:
// 1 A-pair load (mt0/mt1, shared across cfs) + 2 W loads (cf0/cf1, shared
// across mts) -> 4 MFMA. Halves A re-read volume & WG ramp vs r12 (256 blk).
// ---------------------------------------------------------------------------
__global__ __launch_bounds__(512) void step_fused(
    const __bf16* __restrict__ wfh,
    const float* __restrict__ b0,
    const __bf16* __restrict__ af_r, __bf16* __restrict__ af_w,
    const __bf16* __restrict__ xf,
    float* __restrict__ c_st, int t)
{
    __shared__ float part[8][32][34];   // [kq][row 32][col 32 + pad2]

    const int tid  = threadIdx.x;
    const int lane = tid & 63;
    const int kq   = tid >> 6;          // 8 waves = 8 K-slices (5 tiles each)
    const int bi   = blockIdx.x;

    const __bf16* wb  = wfh + ((size_t)bi * NT_ * 2) * 512 + lane * 8;
    const __bf16* xft = xf + ((size_t)t * 8 * 2) * 512;

    f32x4 acc00 = {}, acc01 = {}, acc10 = {}, acc11 = {};   // [mt][cf]

    #pragma unroll
    for (int s = 0; s < 5; ++s) {
        const int K = kq * 5 + s;       // tile 0..39
        const bf16x8 w0 = *(const bf16x8*)(wb + ((size_t)K * 2 + 0) * 512);
        const bf16x8 w1 = *(const bf16x8*)(wb + ((size_t)K * 2 + 1) * 512);
        const __bf16* ab = (K < 32)
            ? (af_r + ((size_t)(K * 2) * 64 + lane) * 8)
            : (xft + ((size_t)((K - 32) * 2) * 64 + lane) * 8);
        const bf16x8 a0 = *(const bf16x8*)ab;            // mt = 0
        const bf16x8 a1 = *(const bf16x8*)(ab + 512);    // mt = 1
        acc00 = __builtin_amdgcn_mfma_f32_16x16x32_bf16(a0, w0, acc00, 0, 0, 0);
        acc01 = __builtin_amdgcn_mfma_f32_16x16x32_bf16(a0, w1, acc01, 0, 0, 0);
        acc10 = __builtin_amdgcn_mfma_f32_16x16x32_bf16(a1, w0, acc10, 0, 0, 0);
        acc11 = __builtin_amdgcn_mfma_f32_16x16x32_bf16(a1, w1, acc11, 0, 0, 0);
    }

    // --- kq-partial exchange (C: col=lane&15, row=(lane>>4)*4+r) ---
    #pragma unroll
    for (int r = 0; r < 4; ++r) {
        const int rr = (lane >> 4) * 4 + r;
        const int cc = lane & 15;
        part[kq][rr][cc]           = acc00[r];
        part[kq][rr][16 + cc]      = acc01[r];
        part[kq][16 + rr][cc]      = acc10[r];
        part[kq][16 + rr][16 + cc] = acc11[r];
    }
    __syncthreads();

    // --- pointwise: 256 threads = 32 b x 8 units; reduce 8 kq partials ---
    if (tid < 256) {
        const int b  = tid >> 3, ul = tid & 7;
        const int u0 = bi * 8;
        float z[4];
        #pragma unroll
        for (int g = 0; g < 4; ++g) {
            const int cl = g * 8 + ul;
            float s2 = b0[g * U_ + u0 + ul];
            #pragma unroll
            for (int q = 0; q < 8; ++q) s2 += part[q][b][cl];
            z[g] = s2;
        }
        const float ii = sigf(z[0]), ff = sigf(z[1]);
        const float gg = tanhfast(z[2]), oo = sigf(z[3]);
        const int ci = b * U_ + u0 + ul;
        const float cv = ff * c_st[ci] + ii * gg;
        c_st[ci] = cv;
        const float hv = oo * tanhfast(cv);
        const int u = u0 + ul;
        const size_t fo = ((size_t)((u >> 5) * 2 + (b >> 4)) * 64
                           + ((u >> 3) & 3) * 16 + (b & 15)) * 8 + (u & 7);
        af_w[fo] = (__bf16)hv;
    }
}

// ---------------------------------------------------------------------------
// Cell-1 z (fp32, off critical path): Pc[b][col] = x_last @ k1 + b1.
// ---------------------------------------------------------------------------
__global__ __launch_bounds__(256) void cell1_gemm(
    const int* __restrict__ tokens, const float* __restrict__ emb,
    const float* __restrict__ k1, const float* __restrict__ b1,
    float* __restrict__ Pc)
{
    const int tid  = threadIdx.x;
    const int lane = tid & 63;
    const int warp = tid >> 6;
    const int j  = blockIdx.x;
    const int ct = j & 15, bg = j >> 4;
    const int b  = bg * 4 + warp;
    const int col = ct * 256 + lane * 4;
    const int tok = tokens[b * T_ + (T_ - 1)];
    const float* wp = k1 + col;
    const float* xp = emb + (size_t)tok * E_;
    float4 acc = *reinterpret_cast<const float4*>(b1 + col);
    #pragma unroll 4
    for (int k4 = 0; k4 < 64; ++k4) {
        const float4 x4 = *reinterpret_cast<const float4*>(xp + k4 * 4);
        const float4 w0 = *reinterpret_cast<const float4*>(wp + (size_t)(k4 * 4 + 0) * FU_);
        const float4 w1 = *reinterpret_cast<const float4*>(wp + (size_t)(k4 * 4 + 1) * FU_);
        const float4 w2 = *reinterpret_cast<const float4*>(wp + (size_t)(k4 * 4 + 2) * FU_);
        const float4 w3 = *reinterpret_cast<const float4*>(wp + (size_t)(k4 * 4 + 3) * FU_);
        acc.x = fmaf(x4.x, w0.x, acc.x); acc.y = fmaf(x4.x, w0.y, acc.y);
        acc.z = fmaf(x4.x, w0.z, acc.z); acc.w = fmaf(x4.x, w0.w, acc.w);
        acc.x = fmaf(x4.y, w1.x, acc.x); acc.y = fmaf(x4.y, w1.y, acc.y);
        acc.z = fmaf(x4.y, w1.z, acc.z); acc.w = fmaf(x4.y, w1.w, acc.w);
        acc.x = fmaf(x4.z, w2.x, acc.x); acc.y = fmaf(x4.z, w2.y, acc.y);
        acc.z = fmaf(x4.z, w2.z, acc.z); acc.w = fmaf(x4.z, w2.w, acc.w);
        acc.x = fmaf(x4.w, w3.x, acc.x); acc.y = fmaf(x4.w, w3.y, acc.y);
        acc.z = fmaf(x4.w, w3.z, acc.z); acc.w = fmaf(x4.w, w3.w, acc.w);
    }
    *reinterpret_cast<float4*>(Pc + (size_t)b * FU_ + col) = acc;
}

// ---------------------------------------------------------------------------
// Final: out[b] = sigmoid( h0.wout[0:U] + h1.wout[U:2U] + bout ).
// h0 from A-fragment layout (bf16 hi); h1 on the fly from Pc.
// ---------------------------------------------------------------------------
__global__ __launch_bounds__(256) void final_kernel(
    const __bf16* __restrict__ hfh,
    const float* __restrict__ Pc,
    const float* __restrict__ wout, const float* __restrict__ bout,
    float* __restrict__ out)
{
    const int b = blockIdx.x;
    const int tid = threadIdx.x;
    float s = 0.f;
    for (int u = tid; u < U_; u += 256) {
        const size_t fo = ((size_t)((u >> 5) * 2 + (b >> 4)) * 64
                           + ((u >> 3) & 3) * 16 + (b & 15)) * 8 + (u & 7);
        const float h0v = (float)hfh[fo];
        const float zi = Pc[(size_t)b * FU_ + u];
        const float zg = Pc[(size_t)b * FU_ + 2 * U_ + u];
        const float zo = Pc[(size_t)b * FU_ + 3 * U_ + u];
        const float c1 = sigf(zi) * tanhf(zg);
        const float h1 = sigf(zo) * tanhf(c1);
        s += h0v * wout[u] + h1 * wout[U_ + u];
    }
    #pragma unroll
    for (int off = 32; off > 0; off >>= 1) s += __shfl_down(s, off, 64);
    __shared__ float partf[4];
    if ((tid & 63) == 0) partf[tid >> 6] = s;
    __syncthreads();
    if (tid == 0) {
        const float tot = partf[0] + partf[1] + partf[2] + partf[3] + bout[0];
        out[b] = 1.f / (1.f + __expf(-tot));
    }
}

extern "C" void kernel_launch(void* const* d_in, const int* in_sizes, int n_in,
                              void* d_out, int out_size, void* d_ws, size_t ws_size,
                              hipStream_t stream) {
    const int*   tokens = (const int*)  d_in[0];
    const float* emb    = (const float*)d_in[1];
    const float* k0     = (const float*)d_in[2];
    const float* rk0    = (const float*)d_in[3];
    const float* b0     = (const float*)d_in[4];
    const float* k1     = (const float*)d_in[5];
    // d_in[6] = rk1 unused: cell 1 runs from zero state.
    const float* b1     = (const float*)d_in[7];
    const float* wout   = (const float*)d_in[8];
    const float* bout   = (const float*)d_in[9];
    float* out = (float*)d_out;

    const size_t BU   = (size_t)B_ * U_;             // 32768
    const size_t BFU  = (size_t)B_ * FU_;            // 131072
    const size_t AFSZ = (size_t)32 * 2 * 64 * 8;     // h-frag elems (64 KB)
    const size_t XFSZ = (size_t)T_ * 8 * 2 * 64 * 8; // x-frag elems (1.6 MB)
    const size_t WSZ  = (size_t)FU_ * VK_;           // 5242880

    float*  c    = (float*)d_ws;               // [32][1024] f32   (128 KB)
    __bf16* af0  = (__bf16*)(c + BU);          // h-frag parity0   (64 KB)
    __bf16* af1  = af0 + AFSZ;                 // h-frag parity1
    __bf16* xf   = af1 + AFSZ;                 // x-frags, all t   (1.6 MB)
    __bf16* wfh  = xf + XFSZ;                  // W frag hi (10.5 MB)
    float*  Pc   = (float*)(wfh + WSZ);        // [32][4096] f32  (512 KB)
    // ws use ~= 12.9 MB

    // zero c + h-frag parity0 (contiguous) every call (replay-safe)
    hipMemsetAsync(c, 0, BU * sizeof(float) + AFSZ * sizeof(__bf16), stream);

    wsplit_kernel<<<2560, 256, 0, stream>>>(rk0, k0, wfh);
    xsplit_all<<<T_, 256, 0, stream>>>(tokens, emb, xf);
    cell1_gemm<<<128, 256, 0, stream>>>(tokens, emb, k1, b1, Pc);

    for (int t = 0; t < T_; ++t) {
        const __bf16* ar = (t & 1) ? af1 : af0;
        __bf16*       aw = (t & 1) ? af0 : af1;
        step_fused<<<NB_, 512, 0, stream>>>(wfh, b0, ar, aw, xf, c, t);
    }
    // T_=250 even: t=249 reads af1, writes af0 -> final h in af0.

    final_kernel<<<B_, 256, 0, stream>>>(af0, Pc, wout, bout, out);
}

// Round 14
// 1090.504 us; speedup vs baseline: 1.0663x; 1.0663x over previous
//
#include <hip/hip_runtime.h>
#include <cmath>

#define B_  32
#define T_  250
#define E_  256
#define U_  1024
#define FU_ 4096   // 4*U
#define VK_ 1280   // virtual K = U + E  ( [rk0 ; k0] )
#define NT_ 40     // W k-tiles (32 h-tiles + 8 x-tiles)

typedef __attribute__((ext_vector_type(8)))  __bf16 bf16x8;
typedef __attribute__((ext_vector_type(4)))  float  f32x4;

__device__ __forceinline__ float sigf(float x)     { return 1.f / (1.f + __expf(-x)); }
__device__ __forceinline__ float tanhfast(float x) { return 1.f - 2.f / (1.f + __expf(2.f * x)); }

// ---------------------------------------------------------------------------
// One-time: transpose weights into MFMA B-fragment order, bf16 hi only
// (r12-proven, absmax 0.0). wfrag[((bi*40 + K)*64 + l)*8 + j], bi = u>>2.
// ---------------------------------------------------------------------------
__global__ __launch_bounds__(256) void wsplit_kernel(
    const float* __restrict__ rk0, const float* __restrict__ k0,
    __bf16* __restrict__ wfh)
{
    __shared__ float tile[32][65];
    const int tid = threadIdx.x;
    const int jt  = blockIdx.x & 63;
    const int kt  = blockIdx.x >> 6;
    const int gk0 = kt * 32;
    const int j0  = jt * 64;

    {
        const int c = tid & 63, r4 = tid >> 6;
        #pragma unroll
        for (int i = 0; i < 8; ++i) {
            const int r  = r4 * 8 + i;
            const int gk = gk0 + r;
            const float* src = (gk < U_) ? (rk0 + (size_t)gk * FU_ + j0 + c)
                                         : (k0 + (size_t)(gk - U_) * FU_ + j0 + c);
            tile[r][c] = *src;
        }
    }
    __syncthreads();
    {
        const int j_loc = tid >> 2, kseg = tid & 3;
        bf16x8 hi;
        #pragma unroll
        for (int i = 0; i < 8; ++i)
            hi[i] = (__bf16)tile[kseg * 8 + i][j_loc];
        const int col = j0 + j_loc;
        const int g   = col >> 10;
        const int u   = col & 1023;
        const int bi  = u >> 2;
        const int c   = g * 4 + (u & 3);
        const int l   = kseg * 16 + c;
        const size_t off = (((size_t)bi * NT_ + kt) * 64 + l) * 8;
        *(bf16x8*)(wfh + off) = hi;
    }
}

// ---------------------------------------------------------------------------
// One-time: x-fragments (bf16 hi) for ALL 250 steps (proven r11-13).
// xf[(((t*8 + Kx)*2 + mt)*64 + lane)*8 + j].
// ---------------------------------------------------------------------------
__global__ __launch_bounds__(256) void xsplit_all(
    const int* __restrict__ tokens, const float* __restrict__ emb,
    __bf16* __restrict__ xf)
{
    const int t   = blockIdx.x;
    const int tid = threadIdx.x;
    const int b   = tid >> 3;
    const int kc  = (tid & 7) * 32;
    const int tok = tokens[b * T_ + t];
    const float* ep = emb + (size_t)tok * E_ + kc;
    const int Kx = kc >> 5;
    const int mt = b >> 4;
    #pragma unroll
    for (int g8 = 0; g8 < 4; ++g8) {
        bf16x8 hi;
        #pragma unroll
        for (int j = 0; j < 8; ++j) hi[j] = (__bf16)ep[g8 * 8 + j];
        const int lane2 = g8 * 16 + (b & 15);
        const size_t off = ((((size_t)t * 8 + Kx) * 2 + mt) * 64 + lane2) * 8;
        *(bf16x8*)(xf + off) = hi;
    }
}

// ---------------------------------------------------------------------------
// Fused LSTM step, launched 250x — EXACT r12 structure (best measured:
// 1126us total; r13's 128-block variant regressed: step kernel is
// latency-bound, keep 256 blocks = 1/CU). Only change: tanhf -> tanhfast.
// Grid 256 x 512. Block bi = units [4bi,4bi+4) x 4 gates, full K=1280.
// Wave = kq (8 x 5 k-tiles); mt inside wave -> 5 W + 10 A loads, 10 MFMA.
// ---------------------------------------------------------------------------
__global__ __launch_bounds__(512) void step_fused(
    const __bf16* __restrict__ wfh,
    const float* __restrict__ b0,
    const __bf16* __restrict__ af_r, __bf16* __restrict__ af_w,
    const __bf16* __restrict__ xf,
    float* __restrict__ c_st, int t)
{
    __shared__ float part[8][32][18];   // [kq][row][col], stride 18

    const int tid  = threadIdx.x;
    const int lane = tid & 63;
    const int kq   = tid >> 6;          // 8 waves = 8 K-slices (5 tiles each)
    const int bi   = blockIdx.x;

    const __bf16* wbh = wfh + ((size_t)bi * NT_) * 512 + lane * 8;
    const __bf16* xft = xf + ((size_t)t * 8 * 2) * 512;

    f32x4 acc0 = {}, acc1 = {};

    #pragma unroll
    for (int s = 0; s < 5; ++s) {
        const int K = kq * 5 + s;       // tile 0..39
        const bf16x8 wh = *(const bf16x8*)(wbh + (size_t)K * 512);
        const __bf16* abase = (K < 32)
            ? (af_r + ((size_t)(K * 2) * 64 + lane) * 8)
            : (xft + ((size_t)((K - 32) * 2) * 64 + lane) * 8);
        const bf16x8 a0 = *(const bf16x8*)abase;            // mt = 0
        const bf16x8 a1 = *(const bf16x8*)(abase + 512);    // mt = 1
        acc0 = __builtin_amdgcn_mfma_f32_16x16x32_bf16(a0, wh, acc0, 0, 0, 0);
        acc1 = __builtin_amdgcn_mfma_f32_16x16x32_bf16(a1, wh, acc1, 0, 0, 0);
    }

    // --- kq-partial exchange (C: col=lane&15, row=(lane>>4)*4+r) ---
    #pragma unroll
    for (int r = 0; r < 4; ++r) {
        const int rr = (lane >> 4) * 4 + r;
        part[kq][rr][lane & 15]      = acc0[r];
        part[kq][16 + rr][lane & 15] = acc1[r];
    }
    __syncthreads();

    // --- pointwise: reduce 8 kq partials, gates, c/h update ---
    if (tid < 128) {
        const int b  = tid >> 2, uu = tid & 3;
        const int u0 = bi * 4;
        float z[4];
        #pragma unroll
        for (int g = 0; g < 4; ++g) {
            const int c = g * 4 + uu;
            float s2 = b0[g * U_ + u0 + uu];
            #pragma unroll
            for (int q = 0; q < 8; ++q) s2 += part[q][b][c];
            z[g] = s2;
        }
        const float ii = sigf(z[0]), ff = sigf(z[1]);
        const float gg = tanhfast(z[2]), oo = sigf(z[3]);
        const int ci = b * U_ + u0 + uu;
        const float cv = ff * c_st[ci] + ii * gg;
        c_st[ci] = cv;
        const float hv = oo * tanhfast(cv);
        const int u = u0 + uu;
        const size_t fo = ((size_t)((u >> 5) * 2 + (b >> 4)) * 64
                           + ((u >> 3) & 3) * 16 + (b & 15)) * 8 + (u & 7);
        af_w[fo] = (__bf16)hv;
    }
}

// ---------------------------------------------------------------------------
// Cell-1 z (fp32, off critical path): Pc[b][col] = x_last @ k1 + b1.
// ---------------------------------------------------------------------------
__global__ __launch_bounds__(256) void cell1_gemm(
    const int* __restrict__ tokens, const float* __restrict__ emb,
    const float* __restrict__ k1, const float* __restrict__ b1,
    float* __restrict__ Pc)
{
    const int tid  = threadIdx.x;
    const int lane = tid & 63;
    const int warp = tid >> 6;
    const int j  = blockIdx.x;
    const int ct = j & 15, bg = j >> 4;
    const int b  = bg * 4 + warp;
    const int col = ct * 256 + lane * 4;
    const int tok = tokens[b * T_ + (T_ - 1)];
    const float* wp = k1 + col;
    const float* xp = emb + (size_t)tok * E_;
    float4 acc = *reinterpret_cast<const float4*>(b1 + col);
    #pragma unroll 4
    for (int k4 = 0; k4 < 64; ++k4) {
        const float4 x4 = *reinterpret_cast<const float4*>(xp + k4 * 4);
        const float4 w0 = *reinterpret_cast<const float4*>(wp + (size_t)(k4 * 4 + 0) * FU_);
        const float4 w1 = *reinterpret_cast<const float4*>(wp + (size_t)(k4 * 4 + 1) * FU_);
        const float4 w2 = *reinterpret_cast<const float4*>(wp + (size_t)(k4 * 4 + 2) * FU_);
        const float4 w3 = *reinterpret_cast<const float4*>(wp + (size_t)(k4 * 4 + 3) * FU_);
        acc.x = fmaf(x4.x, w0.x, acc.x); acc.y = fmaf(x4.x, w0.y, acc.y);
        acc.z = fmaf(x4.x, w0.z, acc.z); acc.w = fmaf(x4.x, w0.w, acc.w);
        acc.x = fmaf(x4.y, w1.x, acc.x); acc.y = fmaf(x4.y, w1.y, acc.y);
        acc.z = fmaf(x4.y, w1.z, acc.z); acc.w = fmaf(x4.y, w1.w, acc.w);
        acc.x = fmaf(x4.z, w2.x, acc.x); acc.y = fmaf(x4.z, w2.y, acc.y);
        acc.z = fmaf(x4.z, w2.z, acc.z); acc.w = fmaf(x4.z, w2.w, acc.w);
        acc.x = fmaf(x4.w, w3.x, acc.x); acc.y = fmaf(x4.w, w3.y, acc.y);
        acc.z = fmaf(x4.w, w3.z, acc.z); acc.w = fmaf(x4.w, w3.w, acc.w);
    }
    *reinterpret_cast<float4*>(Pc + (size_t)b * FU_ + col) = acc;
}

// ---------------------------------------------------------------------------
// Final: out[b] = sigmoid( h0.wout[0:U] + h1.wout[U:2U] + bout ).
// h0 from A-fragment layout (bf16 hi); h1 on the fly from Pc.
// ---------------------------------------------------------------------------
__global__ __launch_bounds__(256) void final_kernel(
    const __bf16* __restrict__ hfh,
    const float* __restrict__ Pc,
    const float* __restrict__ wout, const float* __restrict__ bout,
    float* __restrict__ out)
{
    const int b = blockIdx.x;
    const int tid = threadIdx.x;
    float s = 0.f;
    for (int u = tid; u < U_; u += 256) {
        const size_t fo = ((size_t)((u >> 5) * 2 + (b >> 4)) * 64
                           + ((u >> 3) & 3) * 16 + (b & 15)) * 8 + (u & 7);
        const float h0v = (float)hfh[fo];
        const float zi = Pc[(size_t)b * FU_ + u];
        const float zg = Pc[(size_t)b * FU_ + 2 * U_ + u];
        const float zo = Pc[(size_t)b * FU_ + 3 * U_ + u];
        const float c1 = sigf(zi) * tanhf(zg);
        const float h1 = sigf(zo) * tanhf(c1);
        s += h0v * wout[u] + h1 * wout[U_ + u];
    }
    #pragma unroll
    for (int off = 32; off > 0; off >>= 1) s += __shfl_down(s, off, 64);
    __shared__ float partf[4];
    if ((tid & 63) == 0) partf[tid >> 6] = s;
    __syncthreads();
    if (tid == 0) {
        const float tot = partf[0] + partf[1] + partf[2] + partf[3] + bout[0];
        out[b] = 1.f / (1.f + __expf(-tot));
    }
}

extern "C" void kernel_launch(void* const* d_in, const int* in_sizes, int n_in,
                              void* d_out, int out_size, void* d_ws, size_t ws_size,
                              hipStream_t stream) {
    const int*   tokens = (const int*)  d_in[0];
    const float* emb    = (const float*)d_in[1];
    const float* k0     = (const float*)d_in[2];
    const float* rk0    = (const float*)d_in[3];
    const float* b0     = (const float*)d_in[4];
    const float* k1     = (const float*)d_in[5];
    // d_in[6] = rk1 unused: cell 1 runs from zero state.
    const float* b1     = (const float*)d_in[7];
    const float* wout   = (const float*)d_in[8];
    const float* bout   = (const float*)d_in[9];
    float* out = (float*)d_out;

    const size_t BU   = (size_t)B_ * U_;             // 32768
    const size_t BFU  = (size_t)B_ * FU_;            // 131072
    const size_t AFSZ = (size_t)32 * 2 * 64 * 8;     // h-frag elems (64 KB)
    const size_t XFSZ = (size_t)T_ * 8 * 2 * 64 * 8; // x-frag elems (1.6 MB)
    const size_t WSZ  = (size_t)FU_ * VK_;           // 5242880

    float*  c    = (float*)d_ws;               // [32][1024] f32   (128 KB)
    __bf16* af0  = (__bf16*)(c + BU);          // h-frag parity0   (64 KB)
    __bf16* af1  = af0 + AFSZ;                 // h-frag parity1
    __bf16* xf   = af1 + AFSZ;                 // x-frags, all t   (1.6 MB)
    __bf16* wfh  = xf + XFSZ;                  // W frag hi (10.5 MB)
    float*  Pc   = (float*)(wfh + WSZ);        // [32][4096] f32  (512 KB)
    // ws use ~= 12.9 MB

    // zero c + h-frag parity0 (contiguous) every call (replay-safe)
    hipMemsetAsync(c, 0, BU * sizeof(float) + AFSZ * sizeof(__bf16), stream);

    wsplit_kernel<<<2560, 256, 0, stream>>>(rk0, k0, wfh);
    xsplit_all<<<T_, 256, 0, stream>>>(tokens, emb, xf);
    cell1_gemm<<<128, 256, 0, stream>>>(tokens, emb, k1, b1, Pc);

    for (int t = 0; t < T_; ++t) {
        const __bf16* ar = (t & 1) ? af1 : af0;
        __bf16*       aw = (t & 1) ? af0 : af1;
        step_fused<<<256, 512, 0, stream>>>(wfh, b0, ar, aw, xf, c, t);
    }
    // T_=250 even: t=249 reads af1, writes af0 -> final h in af0.

    final_kernel<<<B_, 256, 0, stream>>>(af0, Pc, wout, bout, out);
}